// Round 4
// baseline (32150.546 us; speedup 1.0000x reference)
//
#include <hip/hip_runtime.h>
#include <cstdint>
#include <cstddef>

// LSTM autoregressive decoder, BATCH=32, T=256, VOCAB=8192, HIDDEN=1024.
// Per step: kA (h@[Wp|Wh] partials, LDS h-broadcast, 4 cols/thread, REGISTER
//           accumulators - all indexing static) ->
//           kB (32 blocks x 1024 thr: logits + gumbel + in-block argmax +
//           one-hot + LSTM cell).
// jax threefry (partitionable variant) reproduced bit-exactly.

namespace {

constexpr int BB = 32;       // batch
constexpr int TT = 256;      // time steps
constexpr int VV = 8192;     // vocab
constexpr int HH = 1024;     // hidden
constexpr int ZC = 4096;     // 4*H
constexpr int NCOL = VV + ZC;   // 12288 columns (logits | z)
constexpr int K0S = 8;       // u-split for K0 (9216/1152)

__host__ __device__ inline uint32_t rotl(uint32_t v, int r) {
  return (v << r) | (v >> (32 - r));
}

// Exact jax threefry2x32 (20 rounds).
__host__ __device__ inline void tf2x32(uint32_t k0, uint32_t k1,
                                       uint32_t x0, uint32_t x1,
                                       uint32_t &o0, uint32_t &o1) {
  const uint32_t ks2 = k0 ^ k1 ^ 0x1BD11BDAu;
  x0 += k0; x1 += k1;
#define R4A { x0+=x1; x1=rotl(x1,13); x1^=x0; x0+=x1; x1=rotl(x1,15); x1^=x0; \
              x0+=x1; x1=rotl(x1,26); x1^=x0; x0+=x1; x1=rotl(x1, 6); x1^=x0; }
#define R4B { x0+=x1; x1=rotl(x1,17); x1^=x0; x0+=x1; x1=rotl(x1,29); x1^=x0; \
              x0+=x1; x1=rotl(x1,16); x1^=x0; x0+=x1; x1=rotl(x1,24); x1^=x0; }
  R4A; x0 += k1;  x1 += ks2 + 1u;
  R4B; x0 += ks2; x1 += k0 + 2u;
  R4A; x0 += k0;  x1 += k1 + 3u;
  R4B; x0 += k1;  x1 += ks2 + 4u;
  R4A; x0 += ks2; x1 += k0 + 5u;
#undef R4A
#undef R4B
  o0 = x0; o1 = x1;
}

__device__ inline float sigf(float x) { return 1.0f / (1.0f + expf(-x)); }

// ---------------------------------------------------------------------------
// K0: z0 partials = x0 @ Wi + h0 @ Wh  (K = VOCAB + HIDDEN = 9216, split x8)
__global__ __launch_bounds__(256) void k0_partial(
    const float* __restrict__ inputs,   // [B][T][V], use t=0
    const float* __restrict__ h0,       // [B][H]
    const float* __restrict__ Wi,       // [V][ZC]
    const float* __restrict__ Wh,       // [H][ZC]
    float* __restrict__ zpart0)         // [K0S][B][ZC]
{
  const int cb = blockIdx.x % (ZC / 64);
  const int s  = blockIdx.x / (ZC / 64);
  const int c  = threadIdx.x & 63;
  const int w  = threadIdx.x >> 6;
  const int col = cb * 64 + c;
  const int u0 = s * 1152 + w * 288;

  float acc[BB];
#pragma unroll
  for (int b = 0; b < BB; ++b) acc[b] = 0.0f;

  for (int ui = 0; ui < 288; ++ui) {
    const int u = u0 + ui;
    const float wv = (u < VV) ? Wi[(size_t)u * ZC + col]
                              : Wh[(size_t)(u - VV) * ZC + col];
#pragma unroll
    for (int b = 0; b < BB; ++b) {
      const float a = (u < VV) ? inputs[(size_t)b * TT * VV + u]
                               : h0[b * HH + (u - VV)];
      acc[b] = fmaf(a, wv, acc[b]);
    }
  }

  __shared__ float red[4][BB][64];   // 32 KiB
#pragma unroll
  for (int b = 0; b < BB; ++b) red[w][b][c] = acc[b];
  __syncthreads();
  for (int i = threadIdx.x; i < BB * 64; i += 256) {
    const int b = i >> 6, cc = i & 63;
    const float s4 = red[0][b][cc] + red[1][b][cc] + red[2][b][cc] + red[3][b][cc];
    zpart0[((size_t)s * BB + b) * ZC + cb * 64 + cc] = s4;
  }
}

// K0b: zfull0[b][j] = bh[j] + sum_s zpart0[s][b][j]
__global__ __launch_bounds__(256) void k0_reduce(
    const float* __restrict__ zpart0, const float* __restrict__ bh,
    float* __restrict__ zfull0)
{
  const int idx = blockIdx.x * 256 + threadIdx.x;  // B*ZC = 131072
  const int b = idx / ZC, j = idx % ZC;
  float s = bh[j];
#pragma unroll
  for (int k = 0; k < K0S; ++k) s += zpart0[((size_t)k * BB + b) * ZC + j];
  zfull0[idx] = s;
}

// kInit: cell for step 0 from zfull0 -> cbuf, hbuf. grid 128 x 256.
__global__ __launch_bounds__(256) void kInit(
    const float* __restrict__ zfull0, const float* __restrict__ c0,
    float* __restrict__ cbuf, float* __restrict__ hbuf)
{
  const int idx = blockIdx.x * 256 + threadIdx.x;   // B*H = 32768
  const int b = idx >> 10, u = idx & 1023;
  const float* z = zfull0 + (size_t)b * ZC;
  const float zi = z[u], zf = z[HH + u], zg = z[2 * HH + u], zo = z[3 * HH + u];
  const float cc = sigf(zf) * c0[idx] + sigf(zi) * tanhf(zg);
  cbuf[idx] = cc;
  hbuf[idx] = sigf(zo) * tanhf(cc);
}

// ---------------------------------------------------------------------------
// kA: part[s][b][col] partials for [h@Wp | h@Wh].
// Block: 256 cols (4/thread as float4), u-slice of HH/SPL; 4 waves split u;
// h staged in LDS (wave-broadcast reads), register accumulators with ALL
// static indexing (rule #20), float4 LDS reduce, coalesced part write.
template <int SPL>
__global__ __launch_bounds__(256, 2) void kA(
    const float* __restrict__ hbuf,     // [B][H]
    const float* __restrict__ Wp,       // [H][V]
    const float* __restrict__ Wh,       // [H][ZC]
    float* __restrict__ part)           // [SPL][B][NCOL]
{
  constexpr int UB = HH / SPL;          // u per block (128 @ SPL=8)
  constexpr int UW = UB / 4;            // u per wave  (32)
  constexpr int UC = UW / 8;            // 8-u chunks  (4)
  constexpr int NCB = NCOL / 256;       // 48 col-blocks

  const int cb   = blockIdx.x % NCB;
  const int s    = blockIdx.x / NCB;
  const int lane = threadIdx.x & 63;
  const int w    = threadIdx.x >> 6;
  const int colbase = cb * 256;

  const float* W; int ldw, wcol0;
  if (colbase < VV) { W = Wp; ldw = VV; wcol0 = colbase + lane * 4; }
  else              { W = Wh; ldw = ZC; wcol0 = colbase - VV + lane * 4; }

  __shared__ __align__(16) float hs[BB][UB];   // 16 KiB @ SPL=8
  __shared__ float4 red4[4][8][64];            // 32 KiB

  const int u0 = s * UB;
  for (int f = threadIdx.x * 4; f < BB * UB; f += 256 * 4) {
    const int b = f / UB, uu = f % UB;
    *(float4*)&hs[b][uu] = *(const float4*)&hbuf[b * HH + u0 + uu];
  }
  __syncthreads();

  float4 acc[BB];
#pragma unroll
  for (int b = 0; b < BB; ++b) acc[b] = make_float4(0.f, 0.f, 0.f, 0.f);

  const float* wp = W + (size_t)(u0 + w * UW) * ldw + wcol0;
#pragma unroll 1
  for (int uc = 0; uc < UC; ++uc) {
    float4 wv[8];
#pragma unroll
    for (int k = 0; k < 8; ++k)
      wv[k] = *(const float4*)&wp[(size_t)(uc * 8 + k) * ldw];
#pragma unroll
    for (int b = 0; b < BB; ++b) {
      const float4 h0v = *(const float4*)&hs[b][w * UW + uc * 8];
      const float4 h1v = *(const float4*)&hs[b][w * UW + uc * 8 + 4];
      float4 a = acc[b];
      a.x = fmaf(wv[0].x, h0v.x, a.x); a.y = fmaf(wv[0].y, h0v.x, a.y);
      a.z = fmaf(wv[0].z, h0v.x, a.z); a.w = fmaf(wv[0].w, h0v.x, a.w);
      a.x = fmaf(wv[1].x, h0v.y, a.x); a.y = fmaf(wv[1].y, h0v.y, a.y);
      a.z = fmaf(wv[1].z, h0v.y, a.z); a.w = fmaf(wv[1].w, h0v.y, a.w);
      a.x = fmaf(wv[2].x, h0v.z, a.x); a.y = fmaf(wv[2].y, h0v.z, a.y);
      a.z = fmaf(wv[2].z, h0v.z, a.z); a.w = fmaf(wv[2].w, h0v.z, a.w);
      a.x = fmaf(wv[3].x, h0v.w, a.x); a.y = fmaf(wv[3].y, h0v.w, a.y);
      a.z = fmaf(wv[3].z, h0v.w, a.z); a.w = fmaf(wv[3].w, h0v.w, a.w);
      a.x = fmaf(wv[4].x, h1v.x, a.x); a.y = fmaf(wv[4].y, h1v.x, a.y);
      a.z = fmaf(wv[4].z, h1v.x, a.z); a.w = fmaf(wv[4].w, h1v.x, a.w);
      a.x = fmaf(wv[5].x, h1v.y, a.x); a.y = fmaf(wv[5].y, h1v.y, a.y);
      a.z = fmaf(wv[5].z, h1v.y, a.z); a.w = fmaf(wv[5].w, h1v.y, a.w);
      a.x = fmaf(wv[6].x, h1v.z, a.x); a.y = fmaf(wv[6].y, h1v.z, a.y);
      a.z = fmaf(wv[6].z, h1v.z, a.z); a.w = fmaf(wv[6].w, h1v.z, a.w);
      a.x = fmaf(wv[7].x, h1v.w, a.x); a.y = fmaf(wv[7].y, h1v.w, a.y);
      a.z = fmaf(wv[7].z, h1v.w, a.z); a.w = fmaf(wv[7].w, h1v.w, a.w);
      acc[b] = a;
    }
  }

  // Cross-wave reduce: 4 rounds of 8 batches. FULLY UNROLLED so acc[] is
  // always statically indexed (otherwise acc spills to scratch - rule #20).
#pragma unroll
  for (int rb = 0; rb < 4; ++rb) {
    __syncthreads();
#pragma unroll
    for (int bl = 0; bl < 8; ++bl) red4[w][bl][lane] = acc[rb * 8 + bl];
    __syncthreads();
    for (int i = threadIdx.x; i < 8 * 64; i += 256) {
      const int bl = i >> 6, cc = i & 63;
      const float4 r0 = red4[0][bl][cc], r1 = red4[1][bl][cc];
      const float4 r2 = red4[2][bl][cc], r3 = red4[3][bl][cc];
      float4 o;
      o.x = (r0.x + r1.x) + (r2.x + r3.x);
      o.y = (r0.y + r1.y) + (r2.y + r3.y);
      o.z = (r0.z + r1.z) + (r2.z + r3.z);
      o.w = (r0.w + r1.w) + (r2.w + r3.w);
      const int b = rb * 8 + bl;
      *(float4*)&part[((size_t)s * BB + b) * NCOL + colbase + cc * 4] = o;
    }
  }
}

// ---------------------------------------------------------------------------
// kB: per-b block (grid=32, 1024 thr): logits = sum_s part + bp -> out;
// gumbel via threefry; in-block argmax (first-index ties); preds zero+onehot;
// then LSTM cell for the next step (u = tid).
__global__ __launch_bounds__(1024) void kB(
    const float* __restrict__ part,     // [spl][B][NCOL]
    const float* __restrict__ bp,       // [V]
    const float* __restrict__ bh,       // [ZC]
    const float* __restrict__ Wi,       // [V][ZC]
    float* __restrict__ logits_out,     // [B][T][V]
    float* __restrict__ preds_out,      // [B][T][V]
    float* __restrict__ cbuf, float* __restrict__ hbuf,   // [B][H]
    uint32_t ck0, uint32_t ck1, int t, int do_cell, int spl)
{
  const int b = blockIdx.x;
  const int tid = threadIdx.x;
  float* lg_row = logits_out + ((size_t)b * TT + t) * VV;
  float* pr_row = preds_out  + ((size_t)b * TT + t) * VV;

  float best = -3.4e38f; int besti = 0x7fffffff;
#pragma unroll 1
  for (int it = 0; it < VV / 1024; ++it) {
    const int v = it * 1024 + tid;
    float lg = bp[v];
    for (int s = 0; s < spl; ++s) lg += part[((size_t)s * BB + b) * NCOL + v];
    lg_row[v] = lg;
    pr_row[v] = 0.0f;
    uint32_t r0, r1;
    tf2x32(ck0, ck1, 0u, (uint32_t)(b * VV + v), r0, r1);
    const uint32_t bits = r0 ^ r1;
    const float u0 = __uint_as_float((bits >> 9) | 0x3f800000u) - 1.0f;
    const float uu = (u0 == 0.0f) ? 1.17549435e-38f : u0;
    const float val = lg - logf(-logf(uu));
    if (val > best) { best = val; besti = v; }   // v ascending -> first max
  }
  // wave reduce (64 lanes)
#pragma unroll
  for (int off = 32; off; off >>= 1) {
    const float vo = __shfl_down(best, off);
    const int   io = __shfl_down(besti, off);
    if (vo > best || (vo == best && io < besti)) { best = vo; besti = io; }
  }
  __shared__ float wv_[16];
  __shared__ int   wi_[16];
  __shared__ int   stok;
  const int wid = tid >> 6, lane = tid & 63;
  if (lane == 0) { wv_[wid] = best; wi_[wid] = besti; }
  __syncthreads();
  if (tid < 64) {
    float v2 = (lane < 16) ? wv_[lane] : -3.4e38f;
    int   i2 = (lane < 16) ? wi_[lane] : 0x7fffffff;
#pragma unroll
    for (int off = 8; off; off >>= 1) {
      const float vo = __shfl_down(v2, off);
      const int   io = __shfl_down(i2, off);
      if (vo > v2 || (vo == v2 && io < i2)) { v2 = vo; i2 = io; }
    }
    if (lane == 0) stok = i2;
  }
  __syncthreads();
  const int tok = stok;
  if (tid == 0) pr_row[tok] = 1.0f;

  if (do_cell) {
    const int u = tid;   // 1024 threads <-> 1024 hidden units
    float zi = bh[u], zf = bh[HH + u], zg = bh[2 * HH + u], zo = bh[3 * HH + u];
    for (int s = 0; s < spl; ++s) {
      const float* p = part + ((size_t)s * BB + b) * NCOL + VV;
      zi += p[u]; zf += p[HH + u]; zg += p[2 * HH + u]; zo += p[3 * HH + u];
    }
    const float* wr = Wi + (size_t)tok * ZC;
    zi += wr[u]; zf += wr[HH + u]; zg += wr[2 * HH + u]; zo += wr[3 * HH + u];
    const float cp = cbuf[b * HH + u];
    const float cc = sigf(zf) * cp + sigf(zi) * tanhf(zg);
    cbuf[b * HH + u] = cc;
    hbuf[b * HH + u] = sigf(zo) * tanhf(cc);
  }
}

}  // namespace

extern "C" void kernel_launch(void* const* d_in, const int* in_sizes, int n_in,
                              void* d_out, int out_size, void* d_ws, size_t ws_size,
                              hipStream_t stream) {
  const float* inputs = (const float*)d_in[0];
  const float* Wi     = (const float*)d_in[1];
  const float* Wh     = (const float*)d_in[2];
  const float* bh     = (const float*)d_in[3];
  const float* Wp     = (const float*)d_in[4];
  const float* bp     = (const float*)d_in[5];
  const float* c0     = (const float*)d_in[6];
  const float* h0     = (const float*)d_in[7];

  float* out_logits = (float*)d_out;
  float* out_preds  = out_logits + (size_t)BB * TT * VV;

  // Choose split-K factor by available workspace.
  const size_t partB8 = (size_t)8 * BB * NCOL * sizeof(float);   // 12.58 MB
  const size_t tailB  = ((size_t)BB * HH * 2) * sizeof(float);
  const int spl = (ws_size >= partB8 + tailB + 1024) ? 8 : 4;
  const size_t partB = (size_t)spl * BB * NCOL * sizeof(float);

  uint8_t* ws = (uint8_t*)d_ws;
  float* part   = (float*)ws;                 // [spl][B][NCOL]
  float* zpart0 = (float*)ws;                 // [K0S][B][ZC] = 4 MB (overlap)
  float* zfull0 = (float*)(ws + 5u * 1024 * 1024);  // 512 KB, inside part
  size_t off = partB;
  float* cbuf   = (float*)(ws + off); off += (size_t)BB * HH * sizeof(float);
  float* hbuf   = (float*)(ws + off); off += (size_t)BB * HH * sizeof(float);

  // Host-side threefry key chain from jax.random.key(42) = (0, 42).
  uint32_t k0 = 0u, k1 = 42u;
  uint32_t ck[TT][2];
  for (int t = 0; t < TT; ++t) {
    uint32_t a, b2; tf2x32(k0, k1, 0u, 1u, a, b2);
    ck[t][0] = a; ck[t][1] = b2;
    uint32_t n0, n1; tf2x32(k0, k1, 0u, 0u, n0, n1);
    k0 = n0; k1 = n1;
  }

  k0_partial<<<(ZC / 64) * K0S, 256, 0, stream>>>(inputs, h0, Wi, Wh, zpart0);
  k0_reduce<<<BB * ZC / 256, 256, 0, stream>>>(zpart0, bh, zfull0);
  kInit<<<BB * HH / 256, 256, 0, stream>>>(zfull0, c0, cbuf, hbuf);

  for (int t = 0; t < TT; ++t) {
    if (spl == 8)
      kA<8><<<(NCOL / 256) * 8, 256, 0, stream>>>(hbuf, Wp, Wh, part);
    else
      kA<4><<<(NCOL / 256) * 4, 256, 0, stream>>>(hbuf, Wp, Wh, part);
    kB<<<BB, 1024, 0, stream>>>(part, bp, bh, Wi, out_logits, out_preds,
                                cbuf, hbuf, ck[t][0], ck[t][1], t,
                                (t < TT - 1) ? 1 : 0, spl);
  }
}

// Round 5
// 13246.205 us; speedup vs baseline: 2.4272x; 2.4272x over previous
//
#include <hip/hip_runtime.h>
#include <cstdint>
#include <cstddef>

// LSTM autoregressive decoder, BATCH=32, T=256, VOCAB=8192, HIDDEN=1024.
// Per step: kA (h@[Wp|Wh] partials; 4 cols/thread; 16-batch x u-half wave
//           quadrants -> acc is only 64 VGPR; LDS h-broadcast 16KB) ->
//           kB (32 blocks x 1024 thr: logits + gumbel + argmax + one-hot +
//           LSTM cell)  [round-2 proven].
// jax threefry (partitionable variant) reproduced bit-exactly.

namespace {

constexpr int BB = 32;       // batch
constexpr int TT = 256;      // time steps
constexpr int VV = 8192;     // vocab
constexpr int HH = 1024;     // hidden
constexpr int ZC = 4096;     // 4*H
constexpr int NCOL = VV + ZC;   // 12288 columns (logits | z)
constexpr int K0S = 8;       // u-split for K0 (9216/1152)

__host__ __device__ inline uint32_t rotl(uint32_t v, int r) {
  return (v << r) | (v >> (32 - r));
}

// Exact jax threefry2x32 (20 rounds).
__host__ __device__ inline void tf2x32(uint32_t k0, uint32_t k1,
                                       uint32_t x0, uint32_t x1,
                                       uint32_t &o0, uint32_t &o1) {
  const uint32_t ks2 = k0 ^ k1 ^ 0x1BD11BDAu;
  x0 += k0; x1 += k1;
#define R4A { x0+=x1; x1=rotl(x1,13); x1^=x0; x0+=x1; x1=rotl(x1,15); x1^=x0; \
              x0+=x1; x1=rotl(x1,26); x1^=x0; x0+=x1; x1=rotl(x1, 6); x1^=x0; }
#define R4B { x0+=x1; x1=rotl(x1,17); x1^=x0; x0+=x1; x1=rotl(x1,29); x1^=x0; \
              x0+=x1; x1=rotl(x1,16); x1^=x0; x0+=x1; x1=rotl(x1,24); x1^=x0; }
  R4A; x0 += k1;  x1 += ks2 + 1u;
  R4B; x0 += ks2; x1 += k0 + 2u;
  R4A; x0 += k0;  x1 += k1 + 3u;
  R4B; x0 += k1;  x1 += ks2 + 4u;
  R4A; x0 += ks2; x1 += k0 + 5u;
#undef R4A
#undef R4B
  o0 = x0; o1 = x1;
}

__device__ inline float sigf(float x) { return 1.0f / (1.0f + expf(-x)); }

// ---------------------------------------------------------------------------
// K0: z0 partials = x0 @ Wi + h0 @ Wh  (K = VOCAB + HIDDEN = 9216, split x8)
__global__ __launch_bounds__(256) void k0_partial(
    const float* __restrict__ inputs,   // [B][T][V], use t=0
    const float* __restrict__ h0,       // [B][H]
    const float* __restrict__ Wi,       // [V][ZC]
    const float* __restrict__ Wh,       // [H][ZC]
    float* __restrict__ zpart0)         // [K0S][B][ZC]
{
  const int cb = blockIdx.x % (ZC / 64);
  const int s  = blockIdx.x / (ZC / 64);
  const int c  = threadIdx.x & 63;
  const int w  = threadIdx.x >> 6;
  const int col = cb * 64 + c;
  const int u0 = s * 1152 + w * 288;

  float acc[BB];
#pragma unroll
  for (int b = 0; b < BB; ++b) acc[b] = 0.0f;

  for (int ui = 0; ui < 288; ++ui) {
    const int u = u0 + ui;
    const float wv = (u < VV) ? Wi[(size_t)u * ZC + col]
                              : Wh[(size_t)(u - VV) * ZC + col];
#pragma unroll
    for (int b = 0; b < BB; ++b) {
      const float a = (u < VV) ? inputs[(size_t)b * TT * VV + u]
                               : h0[b * HH + (u - VV)];
      acc[b] = fmaf(a, wv, acc[b]);
    }
  }

  __shared__ float red[4][BB][64];   // 32 KiB
#pragma unroll
  for (int b = 0; b < BB; ++b) red[w][b][c] = acc[b];
  __syncthreads();
  for (int i = threadIdx.x; i < BB * 64; i += 256) {
    const int b = i >> 6, cc = i & 63;
    const float s4 = red[0][b][cc] + red[1][b][cc] + red[2][b][cc] + red[3][b][cc];
    zpart0[((size_t)s * BB + b) * ZC + cb * 64 + cc] = s4;
  }
}

// K0b: zfull0[b][j] = bh[j] + sum_s zpart0[s][b][j]
__global__ __launch_bounds__(256) void k0_reduce(
    const float* __restrict__ zpart0, const float* __restrict__ bh,
    float* __restrict__ zfull0)
{
  const int idx = blockIdx.x * 256 + threadIdx.x;  // B*ZC = 131072
  const int b = idx / ZC, j = idx % ZC;
  float s = bh[j];
#pragma unroll
  for (int k = 0; k < K0S; ++k) s += zpart0[((size_t)k * BB + b) * ZC + j];
  zfull0[idx] = s;
}

// kInit: cell for step 0 from zfull0 -> cbuf, hbuf. grid 128 x 256.
__global__ __launch_bounds__(256) void kInit(
    const float* __restrict__ zfull0, const float* __restrict__ c0,
    float* __restrict__ cbuf, float* __restrict__ hbuf)
{
  const int idx = blockIdx.x * 256 + threadIdx.x;   // B*H = 32768
  const int b = idx >> 10, u = idx & 1023;
  const float* z = zfull0 + (size_t)b * ZC;
  const float zi = z[u], zf = z[HH + u], zg = z[2 * HH + u], zo = z[3 * HH + u];
  const float cc = sigf(zf) * c0[idx] + sigf(zi) * tanhf(zg);
  cbuf[idx] = cc;
  hbuf[idx] = sigf(zo) * tanhf(cc);
}

// ---------------------------------------------------------------------------
// kA: part[s][b][col] partials for [h@Wp | h@Wh].
// Block: 256 cols x UB u's, 256 thr. Wave quadrants: (bhalf = w&1) owns 16
// batches, (uhalf = w>>1) owns half the u-slice. Thread: 4 cols via float4.
// acc = float4[16] = 64 VGPR (no spill pressure). h broadcast from 16KB LDS;
// same LDS reused (barrier-guarded) as the 16KB float4 reduce buffer.
template <int SPL>
__global__ __launch_bounds__(256, 2) void kA(
    const float* __restrict__ hbuf,     // [B][H]
    const float* __restrict__ Wp,       // [H][V]
    const float* __restrict__ Wh,       // [H][ZC]
    float* __restrict__ part)           // [SPL][B][NCOL]
{
  constexpr int UB  = HH / SPL;         // u per block: 128 (SPL=8)
  constexpr int UWH = UB / 2;           // u per u-half: 64
  constexpr int UC  = UWH / 8;          // 8-u chunks per wave: 8
  constexpr int NCB = NCOL / 256;       // 48 col-blocks

  const int cb    = blockIdx.x % NCB;
  const int s     = blockIdx.x / NCB;
  const int lane  = threadIdx.x & 63;
  const int w     = threadIdx.x >> 6;
  const int uhalf = w >> 1;
  const int bhalf = w & 1;
  const int b0    = bhalf * 16;
  const int colbase = cb * 256;

  const float* W; int ldw, wcol0;
  if (colbase < VV) { W = Wp; ldw = VV; wcol0 = colbase + lane * 4; }
  else              { W = Wh; ldw = ZC; wcol0 = colbase - VV + lane * 4; }

  // hs[b][u] = smem[b*UB + u]  (16 KB @ SPL=8); aliased later as red[]
  __shared__ __align__(16) float smem[BB * UB];

  const int u0 = s * UB;
  for (int f = threadIdx.x * 4; f < BB * UB; f += 1024) {
    const int b = f / UB, uu = f % UB;
    *(float4*)&smem[b * UB + uu] = *(const float4*)&hbuf[b * HH + u0 + uu];
  }
  __syncthreads();

  float4 acc[16];
#pragma unroll
  for (int i = 0; i < 16; ++i) acc[i] = make_float4(0.f, 0.f, 0.f, 0.f);

  const int uloc0 = uhalf * UWH;
  const float* wp = W + (size_t)(u0 + uloc0) * ldw + wcol0;

#pragma unroll 1
  for (int uc = 0; uc < UC; ++uc) {
    float4 wv[8];
#pragma unroll
    for (int k = 0; k < 8; ++k)
      wv[k] = *(const float4*)&wp[(size_t)(uc * 8 + k) * ldw];
#pragma unroll
    for (int bl = 0; bl < 16; ++bl) {
      const float* hrow = &smem[(b0 + bl) * UB + uloc0 + uc * 8];
      const float4 ha = *(const float4*)&hrow[0];   // wave-broadcast reads
      const float4 hb = *(const float4*)&hrow[4];
      float4 a = acc[bl];
      a.x = fmaf(wv[0].x, ha.x, a.x); a.y = fmaf(wv[0].y, ha.x, a.y);
      a.z = fmaf(wv[0].z, ha.x, a.z); a.w = fmaf(wv[0].w, ha.x, a.w);
      a.x = fmaf(wv[1].x, ha.y, a.x); a.y = fmaf(wv[1].y, ha.y, a.y);
      a.z = fmaf(wv[1].z, ha.y, a.z); a.w = fmaf(wv[1].w, ha.y, a.w);
      a.x = fmaf(wv[2].x, ha.z, a.x); a.y = fmaf(wv[2].y, ha.z, a.y);
      a.z = fmaf(wv[2].z, ha.z, a.z); a.w = fmaf(wv[2].w, ha.z, a.w);
      a.x = fmaf(wv[3].x, ha.w, a.x); a.y = fmaf(wv[3].y, ha.w, a.y);
      a.z = fmaf(wv[3].z, ha.w, a.z); a.w = fmaf(wv[3].w, ha.w, a.w);
      a.x = fmaf(wv[4].x, hb.x, a.x); a.y = fmaf(wv[4].y, hb.x, a.y);
      a.z = fmaf(wv[4].z, hb.x, a.z); a.w = fmaf(wv[4].w, hb.x, a.w);
      a.x = fmaf(wv[5].x, hb.y, a.x); a.y = fmaf(wv[5].y, hb.y, a.y);
      a.z = fmaf(wv[5].z, hb.y, a.z); a.w = fmaf(wv[5].w, hb.y, a.w);
      a.x = fmaf(wv[6].x, hb.z, a.x); a.y = fmaf(wv[6].y, hb.z, a.y);
      a.z = fmaf(wv[6].z, hb.z, a.z); a.w = fmaf(wv[6].w, hb.z, a.w);
      a.x = fmaf(wv[7].x, hb.w, a.x); a.y = fmaf(wv[7].y, hb.w, a.y);
      a.z = fmaf(wv[7].z, hb.w, a.z); a.w = fmaf(wv[7].w, hb.w, a.w);
      acc[bl] = a;
    }
  }

  // Epilogue: combine the two u-halves. red[bhalf][uhalf][bl][lane] float4,
  // 2*2*4*64*16B = 16 KB, aliases smem (barrier-guarded). 4 rounds x 4 b's,
  // all indices compile-time static (rule #20).
  float4* red = (float4*)smem;
#pragma unroll
  for (int rb = 0; rb < 4; ++rb) {
    __syncthreads();   // prior round's reads (or hs reads) complete
#pragma unroll
    for (int bl = 0; bl < 4; ++bl)
      red[((bhalf * 2 + uhalf) * 4 + bl) * 64 + lane] = acc[rb * 4 + bl];
    __syncthreads();
#pragma unroll
    for (int rep = 0; rep < 2; ++rep) {
      const int i  = rep * 256 + threadIdx.x;    // 0..511
      const int ln = i & 63, bl = (i >> 6) & 3, bh = i >> 8;
      const float4 r0 = red[((bh * 2 + 0) * 4 + bl) * 64 + ln];
      const float4 r1 = red[((bh * 2 + 1) * 4 + bl) * 64 + ln];
      float4 o;
      o.x = r0.x + r1.x; o.y = r0.y + r1.y;
      o.z = r0.z + r1.z; o.w = r0.w + r1.w;
      const int b = bh * 16 + rb * 4 + bl;
      *(float4*)&part[((size_t)s * BB + b) * NCOL + colbase + ln * 4] = o;
    }
  }
}

// ---------------------------------------------------------------------------
// kB: per-b block (grid=32, 1024 thr): logits = sum_s part + bp -> out;
// gumbel via threefry; in-block argmax (first-index ties); preds zero+onehot;
// then LSTM cell for the next step (u = tid).  [round-2 proven]
__global__ __launch_bounds__(1024) void kB(
    const float* __restrict__ part,     // [spl][B][NCOL]
    const float* __restrict__ bp,       // [V]
    const float* __restrict__ bh,       // [ZC]
    const float* __restrict__ Wi,       // [V][ZC]
    float* __restrict__ logits_out,     // [B][T][V]
    float* __restrict__ preds_out,      // [B][T][V]
    float* __restrict__ cbuf, float* __restrict__ hbuf,   // [B][H]
    uint32_t ck0, uint32_t ck1, int t, int do_cell, int spl)
{
  const int b = blockIdx.x;
  const int tid = threadIdx.x;
  float* lg_row = logits_out + ((size_t)b * TT + t) * VV;
  float* pr_row = preds_out  + ((size_t)b * TT + t) * VV;

  float best = -3.4e38f; int besti = 0x7fffffff;
#pragma unroll 1
  for (int it = 0; it < VV / 1024; ++it) {
    const int v = it * 1024 + tid;
    float lg = bp[v];
    for (int s = 0; s < spl; ++s) lg += part[((size_t)s * BB + b) * NCOL + v];
    lg_row[v] = lg;
    pr_row[v] = 0.0f;
    uint32_t r0, r1;
    tf2x32(ck0, ck1, 0u, (uint32_t)(b * VV + v), r0, r1);
    const uint32_t bits = r0 ^ r1;
    const float u0 = __uint_as_float((bits >> 9) | 0x3f800000u) - 1.0f;
    const float uu = (u0 == 0.0f) ? 1.17549435e-38f : u0;
    const float val = lg - logf(-logf(uu));
    if (val > best) { best = val; besti = v; }   // v ascending -> first max
  }
  // wave reduce (64 lanes)
#pragma unroll
  for (int off = 32; off; off >>= 1) {
    const float vo = __shfl_down(best, off);
    const int   io = __shfl_down(besti, off);
    if (vo > best || (vo == best && io < besti)) { best = vo; besti = io; }
  }
  __shared__ float wv_[16];
  __shared__ int   wi_[16];
  __shared__ int   stok;
  const int wid = tid >> 6, lane = tid & 63;
  if (lane == 0) { wv_[wid] = best; wi_[wid] = besti; }
  __syncthreads();
  if (tid < 64) {
    float v2 = (lane < 16) ? wv_[lane] : -3.4e38f;
    int   i2 = (lane < 16) ? wi_[lane] : 0x7fffffff;
#pragma unroll
    for (int off = 8; off; off >>= 1) {
      const float vo = __shfl_down(v2, off);
      const int   io = __shfl_down(i2, off);
      if (vo > v2 || (vo == v2 && io < i2)) { v2 = vo; i2 = io; }
    }
    if (lane == 0) stok = i2;
  }
  __syncthreads();
  const int tok = stok;
  if (tid == 0) pr_row[tok] = 1.0f;

  if (do_cell) {
    const int u = tid;   // 1024 threads <-> 1024 hidden units
    float zi = bh[u], zf = bh[HH + u], zg = bh[2 * HH + u], zo = bh[3 * HH + u];
    for (int s = 0; s < spl; ++s) {
      const float* p = part + ((size_t)s * BB + b) * NCOL + VV;
      zi += p[u]; zf += p[HH + u]; zg += p[2 * HH + u]; zo += p[3 * HH + u];
    }
    const float* wr = Wi + (size_t)tok * ZC;
    zi += wr[u]; zf += wr[HH + u]; zg += wr[2 * HH + u]; zo += wr[3 * HH + u];
    const float cp = cbuf[b * HH + u];
    const float cc = sigf(zf) * cp + sigf(zi) * tanhf(zg);
    cbuf[b * HH + u] = cc;
    hbuf[b * HH + u] = sigf(zo) * tanhf(cc);
  }
}

}  // namespace

extern "C" void kernel_launch(void* const* d_in, const int* in_sizes, int n_in,
                              void* d_out, int out_size, void* d_ws, size_t ws_size,
                              hipStream_t stream) {
  const float* inputs = (const float*)d_in[0];
  const float* Wi     = (const float*)d_in[1];
  const float* Wh     = (const float*)d_in[2];
  const float* bh     = (const float*)d_in[3];
  const float* Wp     = (const float*)d_in[4];
  const float* bp     = (const float*)d_in[5];
  const float* c0     = (const float*)d_in[6];
  const float* h0     = (const float*)d_in[7];

  float* out_logits = (float*)d_out;
  float* out_preds  = out_logits + (size_t)BB * TT * VV;

  // Choose split-K factor by available workspace (same gate as rounds 3/4).
  const size_t partB8 = (size_t)8 * BB * NCOL * sizeof(float);   // 12.58 MB
  const size_t tailB  = ((size_t)BB * HH * 2) * sizeof(float);
  const int spl = (ws_size >= partB8 + tailB + 1024) ? 8 : 4;
  const size_t partB = (size_t)spl * BB * NCOL * sizeof(float);

  uint8_t* ws = (uint8_t*)d_ws;
  float* part   = (float*)ws;                 // [spl][B][NCOL]
  float* zpart0 = (float*)ws;                 // [K0S][B][ZC] = 4 MB (overlap)
  float* zfull0 = (float*)(ws + 5u * 1024 * 1024);  // 512 KB, inside part
  size_t off = partB;
  float* cbuf   = (float*)(ws + off); off += (size_t)BB * HH * sizeof(float);
  float* hbuf   = (float*)(ws + off); off += (size_t)BB * HH * sizeof(float);

  // Host-side threefry key chain from jax.random.key(42) = (0, 42).
  uint32_t k0 = 0u, k1 = 42u;
  uint32_t ck[TT][2];
  for (int t = 0; t < TT; ++t) {
    uint32_t a, b2; tf2x32(k0, k1, 0u, 1u, a, b2);
    ck[t][0] = a; ck[t][1] = b2;
    uint32_t n0, n1; tf2x32(k0, k1, 0u, 0u, n0, n1);
    k0 = n0; k1 = n1;
  }

  k0_partial<<<(ZC / 64) * K0S, 256, 0, stream>>>(inputs, h0, Wi, Wh, zpart0);
  k0_reduce<<<BB * ZC / 256, 256, 0, stream>>>(zpart0, bh, zfull0);
  kInit<<<BB * HH / 256, 256, 0, stream>>>(zfull0, c0, cbuf, hbuf);

  for (int t = 0; t < TT; ++t) {
    if (spl == 8)
      kA<8><<<(NCOL / 256) * 8, 256, 0, stream>>>(hbuf, Wp, Wh, part);
    else
      kA<4><<<(NCOL / 256) * 4, 256, 0, stream>>>(hbuf, Wp, Wh, part);
    kB<<<BB, 1024, 0, stream>>>(part, bp, bh, Wi, out_logits, out_preds,
                                cbuf, hbuf, ck[t][0], ck[t][1], t,
                                (t < TT - 1) ? 1 : 0, spl);
  }
}

// Round 6
// 10801.405 us; speedup vs baseline: 2.9765x; 1.2263x over previous
//
#include <hip/hip_runtime.h>
#include <cstdint>
#include <cstddef>

// LSTM autoregressive decoder, BATCH=32, T=256, VOCAB=8192, HIDDEN=1024.
// Step pipeline (R1-proven 3-kernel split, all partial loops COMPILE-TIME):
//   K1 (32 blocks): finalize tok(t-1), preds one-hot, z-assemble, LSTM cell
//   kA (48*SPL blocks): h@[Wp|Wh] partials, LDS h-broadcast, 4 cols/thread
//   K3 (1024 blocks): logits + gumbel + argmax partials, preds zero
// jax threefry (partitionable variant) reproduced bit-exactly.

namespace {

constexpr int BB = 32;       // batch
constexpr int TT = 256;      // time steps
constexpr int VV = 8192;     // vocab
constexpr int HH = 1024;     // hidden
constexpr int ZC = 4096;     // 4*H
constexpr int NCOL = VV + ZC;   // 12288 columns (logits | z)
constexpr int K0S = 8;       // u-split for K0 (9216/1152)

__host__ __device__ inline uint32_t rotl(uint32_t v, int r) {
  return (v << r) | (v >> (32 - r));
}

// Exact jax threefry2x32 (20 rounds).
__host__ __device__ inline void tf2x32(uint32_t k0, uint32_t k1,
                                       uint32_t x0, uint32_t x1,
                                       uint32_t &o0, uint32_t &o1) {
  const uint32_t ks2 = k0 ^ k1 ^ 0x1BD11BDAu;
  x0 += k0; x1 += k1;
#define R4A { x0+=x1; x1=rotl(x1,13); x1^=x0; x0+=x1; x1=rotl(x1,15); x1^=x0; \
              x0+=x1; x1=rotl(x1,26); x1^=x0; x0+=x1; x1=rotl(x1, 6); x1^=x0; }
#define R4B { x0+=x1; x1=rotl(x1,17); x1^=x0; x0+=x1; x1=rotl(x1,29); x1^=x0; \
              x0+=x1; x1=rotl(x1,16); x1^=x0; x0+=x1; x1=rotl(x1,24); x1^=x0; }
  R4A; x0 += k1;  x1 += ks2 + 1u;
  R4B; x0 += ks2; x1 += k0 + 2u;
  R4A; x0 += k0;  x1 += k1 + 3u;
  R4B; x0 += k1;  x1 += ks2 + 4u;
  R4A; x0 += ks2; x1 += k0 + 5u;
#undef R4A
#undef R4B
  o0 = x0; o1 = x1;
}

__device__ inline float sigf(float x) { return 1.0f / (1.0f + expf(-x)); }

// ---------------------------------------------------------------------------
// K0: z0 partials = x0 @ Wi + h0 @ Wh  (K = VOCAB + HIDDEN = 9216, split x8)
__global__ __launch_bounds__(256) void k0_partial(
    const float* __restrict__ inputs,   // [B][T][V], use t=0
    const float* __restrict__ h0,       // [B][H]
    const float* __restrict__ Wi,       // [V][ZC]
    const float* __restrict__ Wh,       // [H][ZC]
    float* __restrict__ zpart0)         // [K0S][B][ZC]
{
  const int cb = blockIdx.x % (ZC / 64);
  const int s  = blockIdx.x / (ZC / 64);
  const int c  = threadIdx.x & 63;
  const int w  = threadIdx.x >> 6;
  const int col = cb * 64 + c;
  const int u0 = s * 1152 + w * 288;

  float acc[BB];
#pragma unroll
  for (int b = 0; b < BB; ++b) acc[b] = 0.0f;

  for (int ui = 0; ui < 288; ++ui) {
    const int u = u0 + ui;
    const float wv = (u < VV) ? Wi[(size_t)u * ZC + col]
                              : Wh[(size_t)(u - VV) * ZC + col];
#pragma unroll
    for (int b = 0; b < BB; ++b) {
      const float a = (u < VV) ? inputs[(size_t)b * TT * VV + u]
                               : h0[b * HH + (u - VV)];
      acc[b] = fmaf(a, wv, acc[b]);
    }
  }

  __shared__ float red[4][BB][64];   // 32 KiB
#pragma unroll
  for (int b = 0; b < BB; ++b) red[w][b][c] = acc[b];
  __syncthreads();
  for (int i = threadIdx.x; i < BB * 64; i += 256) {
    const int b = i >> 6, cc = i & 63;
    const float s4 = red[0][b][cc] + red[1][b][cc] + red[2][b][cc] + red[3][b][cc];
    zpart0[((size_t)s * BB + b) * ZC + cb * 64 + cc] = s4;
  }
}

// K0b: zfull0[b][j] = bh[j] + sum_s zpart0[s][b][j]
__global__ __launch_bounds__(256) void k0_reduce(
    const float* __restrict__ zpart0, const float* __restrict__ bh,
    float* __restrict__ zfull0)
{
  const int idx = blockIdx.x * 256 + threadIdx.x;  // B*ZC = 131072
  const int b = idx / ZC, j = idx % ZC;
  float s = bh[j];
#pragma unroll
  for (int k = 0; k < K0S; ++k) s += zpart0[((size_t)k * BB + b) * ZC + j];
  zfull0[idx] = s;
}

// ---------------------------------------------------------------------------
// K1: finalize tok(t-1) from argmax partials, write preds one-hot (t-1),
//     assemble z_t (COMPILE-TIME SPL unrolled partial sums + bh + Wi[tok])
//     and run LSTM cell -> c,h.  grid: B blocks, 256 threads.  [R1-proven]
template <int SPL>
__global__ __launch_bounds__(256) void k1_cell(
    const float* __restrict__ part,     // [SPL][B][NCOL]
    const float* __restrict__ zfull0,   // [B][ZC] (t==0 only)
    const float* __restrict__ bh,       // [ZC]
    const float* __restrict__ Wi,       // [V][ZC]
    const float* __restrict__ c0,       // [B][H]
    const float* __restrict__ argval,   // [B][32]
    const int*   __restrict__ argidx,   // [B][32]
    float* __restrict__ cbuf, float* __restrict__ hbuf,   // [B][H]
    float* __restrict__ preds_out,      // [B][T][V]
    int t)
{
  const int b = blockIdx.x;
  __shared__ int tok_sh;
  if (t > 0) {
    if (threadIdx.x < 64) {
      const int lane = threadIdx.x;
      float v = -3.4e38f; int idx = 0x7fffffff;
      if (lane < 32) { v = argval[b * 32 + lane]; idx = argidx[b * 32 + lane]; }
#pragma unroll
      for (int off = 16; off; off >>= 1) {
        const float vo = __shfl_down(v, off);
        const int   io = __shfl_down(idx, off);
        if (vo > v || (vo == v && io < idx)) { v = vo; idx = io; }
      }
      if (lane == 0) tok_sh = idx;
    }
    __syncthreads();
  }
  const int tok = (t > 0) ? tok_sh : 0;
  if (t > 0 && threadIdx.x == 0) {
    preds_out[((size_t)b * TT + (t - 1)) * VV + tok] = 1.0f;
  }

  for (int u = threadIdx.x; u < HH; u += 256) {
    float zi, zf, zg, zo;
    if (t == 0) {
      const float* z0 = zfull0 + (size_t)b * ZC;
      zi = z0[u]; zf = z0[HH + u]; zg = z0[2 * HH + u]; zo = z0[3 * HH + u];
    } else {
      zi = bh[u]; zf = bh[HH + u]; zg = bh[2 * HH + u]; zo = bh[3 * HH + u];
#pragma unroll
      for (int s = 0; s < SPL; ++s) {
        const float* p = part + ((size_t)s * BB + b) * NCOL + VV;
        zi += p[u]; zf += p[HH + u]; zg += p[2 * HH + u]; zo += p[3 * HH + u];
      }
      const float* wrow = Wi + (size_t)tok * ZC;
      zi += wrow[u]; zf += wrow[HH + u]; zg += wrow[2 * HH + u]; zo += wrow[3 * HH + u];
    }
    const float cprev = (t == 0) ? c0[b * HH + u] : cbuf[b * HH + u];
    const float cc = sigf(zf) * cprev + sigf(zi) * tanhf(zg);
    const float hh = sigf(zo) * tanhf(cc);
    cbuf[b * HH + u] = cc;
    hbuf[b * HH + u] = hh;
  }
}

// ---------------------------------------------------------------------------
// kA: part[s][b][col] partials for [h@Wp | h@Wh].  [R5-proven]
// Block: 256 cols x UB u's, 256 thr. Wave quadrants: (bhalf = w&1) owns 16
// batches, (uhalf = w>>1) owns half the u-slice. Thread: 4 cols via float4.
// acc = float4[16] = 64 VGPR. h broadcast from LDS; LDS reused as reduce buf.
template <int SPL>
__global__ __launch_bounds__(256, 2) void kA(
    const float* __restrict__ hbuf,     // [B][H]
    const float* __restrict__ Wp,       // [H][V]
    const float* __restrict__ Wh,       // [H][ZC]
    float* __restrict__ part)           // [SPL][B][NCOL]
{
  constexpr int UB  = HH / SPL;         // u per block: 128 (SPL=8)
  constexpr int UWH = UB / 2;           // u per u-half: 64
  constexpr int UC  = UWH / 8;          // 8-u chunks per wave: 8
  constexpr int NCB = NCOL / 256;       // 48 col-blocks

  const int cb    = blockIdx.x % NCB;
  const int s     = blockIdx.x / NCB;
  const int lane  = threadIdx.x & 63;
  const int w     = threadIdx.x >> 6;
  const int uhalf = w >> 1;
  const int bhalf = w & 1;
  const int b0    = bhalf * 16;
  const int colbase = cb * 256;

  const float* W; int ldw, wcol0;
  if (colbase < VV) { W = Wp; ldw = VV; wcol0 = colbase + lane * 4; }
  else              { W = Wh; ldw = ZC; wcol0 = colbase - VV + lane * 4; }

  __shared__ __align__(16) float smem[BB * UB];   // 16 KB @ SPL=8

  const int u0 = s * UB;
  for (int f = threadIdx.x * 4; f < BB * UB; f += 1024) {
    const int b = f / UB, uu = f % UB;
    *(float4*)&smem[b * UB + uu] = *(const float4*)&hbuf[b * HH + u0 + uu];
  }
  __syncthreads();

  float4 acc[16];
#pragma unroll
  for (int i = 0; i < 16; ++i) acc[i] = make_float4(0.f, 0.f, 0.f, 0.f);

  const int uloc0 = uhalf * UWH;
  const float* wp = W + (size_t)(u0 + uloc0) * ldw + wcol0;

#pragma unroll 1
  for (int uc = 0; uc < UC; ++uc) {
    float4 wv[8];
#pragma unroll
    for (int k = 0; k < 8; ++k)
      wv[k] = *(const float4*)&wp[(size_t)(uc * 8 + k) * ldw];
#pragma unroll
    for (int bl = 0; bl < 16; ++bl) {
      const float* hrow = &smem[(b0 + bl) * UB + uloc0 + uc * 8];
      const float4 ha = *(const float4*)&hrow[0];   // wave-broadcast reads
      const float4 hb = *(const float4*)&hrow[4];
      float4 a = acc[bl];
      a.x = fmaf(wv[0].x, ha.x, a.x); a.y = fmaf(wv[0].y, ha.x, a.y);
      a.z = fmaf(wv[0].z, ha.x, a.z); a.w = fmaf(wv[0].w, ha.x, a.w);
      a.x = fmaf(wv[1].x, ha.y, a.x); a.y = fmaf(wv[1].y, ha.y, a.y);
      a.z = fmaf(wv[1].z, ha.y, a.z); a.w = fmaf(wv[1].w, ha.y, a.w);
      a.x = fmaf(wv[2].x, ha.z, a.x); a.y = fmaf(wv[2].y, ha.z, a.y);
      a.z = fmaf(wv[2].z, ha.z, a.z); a.w = fmaf(wv[2].w, ha.z, a.w);
      a.x = fmaf(wv[3].x, ha.w, a.x); a.y = fmaf(wv[3].y, ha.w, a.y);
      a.z = fmaf(wv[3].z, ha.w, a.z); a.w = fmaf(wv[3].w, ha.w, a.w);
      a.x = fmaf(wv[4].x, hb.x, a.x); a.y = fmaf(wv[4].y, hb.x, a.y);
      a.z = fmaf(wv[4].z, hb.x, a.z); a.w = fmaf(wv[4].w, hb.x, a.w);
      a.x = fmaf(wv[5].x, hb.y, a.x); a.y = fmaf(wv[5].y, hb.y, a.y);
      a.z = fmaf(wv[5].z, hb.y, a.z); a.w = fmaf(wv[5].w, hb.y, a.w);
      a.x = fmaf(wv[6].x, hb.z, a.x); a.y = fmaf(wv[6].y, hb.z, a.y);
      a.z = fmaf(wv[6].z, hb.z, a.z); a.w = fmaf(wv[6].w, hb.z, a.w);
      a.x = fmaf(wv[7].x, hb.w, a.x); a.y = fmaf(wv[7].y, hb.w, a.y);
      a.z = fmaf(wv[7].z, hb.w, a.z); a.w = fmaf(wv[7].w, hb.w, a.w);
      acc[bl] = a;
    }
  }

  // Epilogue: combine the two u-halves via LDS alias (barrier-guarded).
  // All acc[] indices compile-time static (rule #20).
  float4* red = (float4*)smem;
#pragma unroll
  for (int rb = 0; rb < 4; ++rb) {
    __syncthreads();
#pragma unroll
    for (int bl = 0; bl < 4; ++bl)
      red[((bhalf * 2 + uhalf) * 4 + bl) * 64 + lane] = acc[rb * 4 + bl];
    __syncthreads();
#pragma unroll
    for (int rep = 0; rep < 2; ++rep) {
      const int i  = rep * 256 + threadIdx.x;    // 0..511
      const int ln = i & 63, bl = (i >> 6) & 3, bh2 = i >> 8;
      const float4 r0 = red[((bh2 * 2 + 0) * 4 + bl) * 64 + ln];
      const float4 r1 = red[((bh2 * 2 + 1) * 4 + bl) * 64 + ln];
      float4 o;
      o.x = r0.x + r1.x; o.y = r0.y + r1.y;
      o.z = r0.z + r1.z; o.w = r0.w + r1.w;
      const int b = bh2 * 16 + rb * 4 + bl;
      *(float4*)&part[((size_t)s * BB + b) * NCOL + colbase + ln * 4] = o;
    }
  }
}

// ---------------------------------------------------------------------------
// K3: logits = sum_s part (COMPILE-TIME unroll) + bp -> out; preds zero;
// gumbel via threefry; per-block argmax partial.  grid: B*32 = 1024 blocks,
// 256 threads, ONE column per thread.  [R1-proven]
template <int SPL>
__global__ __launch_bounds__(256) void k3_logits(
    const float* __restrict__ part,     // [SPL][B][NCOL]
    const float* __restrict__ bp,       // [V]
    float* __restrict__ logits_out,     // [B][T][V]
    float* __restrict__ preds_out,      // [B][T][V]
    float* __restrict__ argval, int* __restrict__ argidx,   // [B][32]
    uint32_t ck0, uint32_t ck1, int t)
{
  const int b  = blockIdx.x >> 5;
  const int ch = blockIdx.x & 31;
  const int v  = ch * 256 + threadIdx.x;

  float lg = bp[v];
#pragma unroll
  for (int s = 0; s < SPL; ++s) lg += part[((size_t)s * BB + b) * NCOL + v];
  logits_out[((size_t)b * TT + t) * VV + v] = lg;
  preds_out [((size_t)b * TT + t) * VV + v] = 0.0f;

  // gumbel: jax partitionable random_bits, 32-bit -> o0 ^ o1
  const uint32_t j = (uint32_t)(b * VV + v);
  uint32_t r0, r1;
  tf2x32(ck0, ck1, 0u, j, r0, r1);
  const uint32_t bits = r0 ^ r1;
  const float u0 = __uint_as_float((bits >> 9) | 0x3f800000u) - 1.0f;
  const float uu = (u0 == 0.0f) ? 1.17549435e-38f : u0;
  const float g = -logf(-logf(uu));
  const float val = lg + g;

  __shared__ float sval[256];
  __shared__ int   sidx[256];
  sval[threadIdx.x] = val;
  sidx[threadIdx.x] = v;
  __syncthreads();
#pragma unroll
  for (int off = 128; off; off >>= 1) {
    if (threadIdx.x < off) {
      const float vo = sval[threadIdx.x + off];
      const int   io = sidx[threadIdx.x + off];
      if (vo > sval[threadIdx.x] ||
          (vo == sval[threadIdx.x] && io < sidx[threadIdx.x])) {
        sval[threadIdx.x] = vo; sidx[threadIdx.x] = io;
      }
    }
    __syncthreads();
  }
  if (threadIdx.x == 0) {
    argval[b * 32 + ch] = sval[0];
    argidx[b * 32 + ch] = sidx[0];
  }
}

// Final preds row (t = T-1).  [R1-proven]
__global__ __launch_bounds__(64) void kfinal(
    const float* __restrict__ argval, const int* __restrict__ argidx,
    float* __restrict__ preds_out)
{
  const int b = blockIdx.x, lane = threadIdx.x;
  float v = -3.4e38f; int idx = 0x7fffffff;
  if (lane < 32) { v = argval[b * 32 + lane]; idx = argidx[b * 32 + lane]; }
#pragma unroll
  for (int off = 16; off; off >>= 1) {
    const float vo = __shfl_down(v, off);
    const int   io = __shfl_down(idx, off);
    if (vo > v || (vo == v && io < idx)) { v = vo; idx = io; }
  }
  if (lane == 0) preds_out[((size_t)b * TT + (TT - 1)) * VV + idx] = 1.0f;
}

}  // namespace

extern "C" void kernel_launch(void* const* d_in, const int* in_sizes, int n_in,
                              void* d_out, int out_size, void* d_ws, size_t ws_size,
                              hipStream_t stream) {
  const float* inputs = (const float*)d_in[0];
  const float* Wi     = (const float*)d_in[1];
  const float* Wh     = (const float*)d_in[2];
  const float* bh     = (const float*)d_in[3];
  const float* Wp     = (const float*)d_in[4];
  const float* bp     = (const float*)d_in[5];
  const float* c0     = (const float*)d_in[6];
  const float* h0     = (const float*)d_in[7];

  float* out_logits = (float*)d_out;
  float* out_preds  = out_logits + (size_t)BB * TT * VV;

  // Choose split-K factor by available workspace.
  const size_t partB8 = (size_t)8 * BB * NCOL * sizeof(float);   // 12.58 MB
  const size_t tailB  = ((size_t)BB * ZC + (size_t)BB * HH * 2 +
                         (size_t)BB * 32 * 2) * sizeof(float);
  const int spl = (ws_size >= partB8 + tailB + 1024) ? 8 : 4;
  const size_t partB = (size_t)spl * BB * NCOL * sizeof(float);

  uint8_t* ws = (uint8_t*)d_ws;
  float* part   = (float*)ws;                 // [spl][B][NCOL]
  float* zpart0 = (float*)ws;                 // [K0S][B][ZC] = 4 MB (overlap)
  size_t off = partB;
  float* zfull0 = (float*)(ws + off); off += (size_t)BB * ZC * sizeof(float);
  float* cbuf   = (float*)(ws + off); off += (size_t)BB * HH * sizeof(float);
  float* hbuf   = (float*)(ws + off); off += (size_t)BB * HH * sizeof(float);
  float* argval = (float*)(ws + off); off += (size_t)BB * 32 * sizeof(float);
  int*   argidx = (int*)  (ws + off); off += (size_t)BB * 32 * sizeof(int);

  // Host-side threefry key chain from jax.random.key(42) = (0, 42).
  uint32_t k0 = 0u, k1 = 42u;
  uint32_t ck[TT][2];
  for (int t = 0; t < TT; ++t) {
    uint32_t a, b2; tf2x32(k0, k1, 0u, 1u, a, b2);
    ck[t][0] = a; ck[t][1] = b2;
    uint32_t n0, n1; tf2x32(k0, k1, 0u, 0u, n0, n1);
    k0 = n0; k1 = n1;
  }

  k0_partial<<<(ZC / 64) * K0S, 256, 0, stream>>>(inputs, h0, Wi, Wh, zpart0);
  k0_reduce<<<BB * ZC / 256, 256, 0, stream>>>(zpart0, bh, zfull0);

  for (int t = 0; t < TT; ++t) {
    if (spl == 8) {
      k1_cell<8><<<BB, 256, 0, stream>>>(part, zfull0, bh, Wi, c0, argval,
                                         argidx, cbuf, hbuf, out_preds, t);
      kA<8><<<(NCOL / 256) * 8, 256, 0, stream>>>(hbuf, Wp, Wh, part);
      k3_logits<8><<<BB * 32, 256, 0, stream>>>(part, bp, out_logits, out_preds,
                                                argval, argidx, ck[t][0], ck[t][1], t);
    } else {
      k1_cell<4><<<BB, 256, 0, stream>>>(part, zfull0, bh, Wi, c0, argval,
                                         argidx, cbuf, hbuf, out_preds, t);
      kA<4><<<(NCOL / 256) * 4, 256, 0, stream>>>(hbuf, Wp, Wh, part);
      k3_logits<4><<<BB * 32, 256, 0, stream>>>(part, bp, out_logits, out_preds,
                                                argval, argidx, ck[t][0], ck[t][1], t);
    }
  }
  kfinal<<<BB, 64, 0, stream>>>(argval, argidx, out_preds);
}

// Round 7
// 9199.477 us; speedup vs baseline: 3.4948x; 1.1741x over previous
//
#include <hip/hip_runtime.h>
#include <cstdint>
#include <cstddef>

// LSTM autoregressive decoder, BATCH=32, T=256, VOCAB=8192, HIDDEN=1024.
// Step pipeline (3 kernels, SPL=4 forced - part fits the proven ws budget):
//   K1 (32 blocks): finalize tok(t-1), preds one-hot, z-assemble, LSTM cell
//   kA (768 blocks = 96 colblk x 4 uslice x 2 bgroup): h@[Wp|Wh] partials
//   K3 (1024 blocks): logits + gumbel + argmax partials, preds zero
// jax threefry (partitionable variant) reproduced bit-exactly.

namespace {

constexpr int BB = 32;       // batch
constexpr int TT = 256;      // time steps
constexpr int VV = 8192;     // vocab
constexpr int HH = 1024;     // hidden
constexpr int ZC = 4096;     // 4*H
constexpr int NCOL = VV + ZC;   // 12288 columns (logits | z)
constexpr int SPL = 4;       // u-split (part = [4][32][12288] = 6.29 MB)
constexpr int K0S = 8;       // u-split for K0 (9216/1152)

__host__ __device__ inline uint32_t rotl(uint32_t v, int r) {
  return (v << r) | (v >> (32 - r));
}

// Exact jax threefry2x32 (20 rounds).
__host__ __device__ inline void tf2x32(uint32_t k0, uint32_t k1,
                                       uint32_t x0, uint32_t x1,
                                       uint32_t &o0, uint32_t &o1) {
  const uint32_t ks2 = k0 ^ k1 ^ 0x1BD11BDAu;
  x0 += k0; x1 += k1;
#define R4A { x0+=x1; x1=rotl(x1,13); x1^=x0; x0+=x1; x1=rotl(x1,15); x1^=x0; \
              x0+=x1; x1=rotl(x1,26); x1^=x0; x0+=x1; x1=rotl(x1, 6); x1^=x0; }
#define R4B { x0+=x1; x1=rotl(x1,17); x1^=x0; x0+=x1; x1=rotl(x1,29); x1^=x0; \
              x0+=x1; x1=rotl(x1,16); x1^=x0; x0+=x1; x1=rotl(x1,24); x1^=x0; }
  R4A; x0 += k1;  x1 += ks2 + 1u;
  R4B; x0 += ks2; x1 += k0 + 2u;
  R4A; x0 += k0;  x1 += k1 + 3u;
  R4B; x0 += k1;  x1 += ks2 + 4u;
  R4A; x0 += ks2; x1 += k0 + 5u;
#undef R4A
#undef R4B
  o0 = x0; o1 = x1;
}

__device__ inline float sigf(float x) { return 1.0f / (1.0f + expf(-x)); }

// ---------------------------------------------------------------------------
// K0: z0 partials = x0 @ Wi + h0 @ Wh  (K = VOCAB + HIDDEN = 9216, split x8)
__global__ __launch_bounds__(256) void k0_partial(
    const float* __restrict__ inputs,   // [B][T][V], use t=0
    const float* __restrict__ h0,       // [B][H]
    const float* __restrict__ Wi,       // [V][ZC]
    const float* __restrict__ Wh,       // [H][ZC]
    float* __restrict__ zpart0)         // [K0S][B][ZC]
{
  const int cb = blockIdx.x % (ZC / 64);
  const int s  = blockIdx.x / (ZC / 64);
  const int c  = threadIdx.x & 63;
  const int w  = threadIdx.x >> 6;
  const int col = cb * 64 + c;
  const int u0 = s * 1152 + w * 288;

  float acc[BB];
#pragma unroll
  for (int b = 0; b < BB; ++b) acc[b] = 0.0f;

  for (int ui = 0; ui < 288; ++ui) {
    const int u = u0 + ui;
    const float wv = (u < VV) ? Wi[(size_t)u * ZC + col]
                              : Wh[(size_t)(u - VV) * ZC + col];
#pragma unroll
    for (int b = 0; b < BB; ++b) {
      const float a = (u < VV) ? inputs[(size_t)b * TT * VV + u]
                               : h0[b * HH + (u - VV)];
      acc[b] = fmaf(a, wv, acc[b]);
    }
  }

  __shared__ float red[4][BB][64];   // 32 KiB
#pragma unroll
  for (int b = 0; b < BB; ++b) red[w][b][c] = acc[b];
  __syncthreads();
  for (int i = threadIdx.x; i < BB * 64; i += 256) {
    const int b = i >> 6, cc = i & 63;
    const float s4 = red[0][b][cc] + red[1][b][cc] + red[2][b][cc] + red[3][b][cc];
    zpart0[((size_t)s * BB + b) * ZC + cb * 64 + cc] = s4;
  }
}

// K0b: zfull0[b][j] = bh[j] + sum_s zpart0[s][b][j]
__global__ __launch_bounds__(256) void k0_reduce(
    const float* __restrict__ zpart0, const float* __restrict__ bh,
    float* __restrict__ zfull0)
{
  const int idx = blockIdx.x * 256 + threadIdx.x;  // B*ZC = 131072
  const int b = idx / ZC, j = idx % ZC;
  float s = bh[j];
#pragma unroll
  for (int k = 0; k < K0S; ++k) s += zpart0[((size_t)k * BB + b) * ZC + j];
  zfull0[idx] = s;
}

// ---------------------------------------------------------------------------
// K1: finalize tok(t-1), preds one-hot (t-1), z-assemble (static SPL unroll)
// + LSTM cell.  grid: B blocks, 256 threads.  [R1/R6-proven]
__global__ __launch_bounds__(256) void k1_cell(
    const float* __restrict__ part,     // [SPL][B][NCOL]
    const float* __restrict__ zfull0,   // [B][ZC] (t==0 only)
    const float* __restrict__ bh,       // [ZC]
    const float* __restrict__ Wi,       // [V][ZC]
    const float* __restrict__ c0,       // [B][H]
    const float* __restrict__ argval,   // [B][32]
    const int*   __restrict__ argidx,   // [B][32]
    float* __restrict__ cbuf, float* __restrict__ hbuf,   // [B][H]
    float* __restrict__ preds_out,      // [B][T][V]
    int t)
{
  const int b = blockIdx.x;
  __shared__ int tok_sh;
  if (t > 0) {
    if (threadIdx.x < 64) {
      const int lane = threadIdx.x;
      float v = -3.4e38f; int idx = 0x7fffffff;
      if (lane < 32) { v = argval[b * 32 + lane]; idx = argidx[b * 32 + lane]; }
#pragma unroll
      for (int off = 16; off; off >>= 1) {
        const float vo = __shfl_down(v, off);
        const int   io = __shfl_down(idx, off);
        if (vo > v || (vo == v && io < idx)) { v = vo; idx = io; }
      }
      if (lane == 0) tok_sh = idx;
    }
    __syncthreads();
  }
  const int tok = (t > 0) ? tok_sh : 0;
  if (t > 0 && threadIdx.x == 0) {
    preds_out[((size_t)b * TT + (t - 1)) * VV + tok] = 1.0f;
  }

  for (int u = threadIdx.x; u < HH; u += 256) {
    float zi, zf, zg, zo;
    if (t == 0) {
      const float* z0 = zfull0 + (size_t)b * ZC;
      zi = z0[u]; zf = z0[HH + u]; zg = z0[2 * HH + u]; zo = z0[3 * HH + u];
    } else {
      zi = bh[u]; zf = bh[HH + u]; zg = bh[2 * HH + u]; zo = bh[3 * HH + u];
#pragma unroll
      for (int s = 0; s < SPL; ++s) {
        const float* p = part + ((size_t)s * BB + b) * NCOL + VV;
        zi += p[u]; zf += p[HH + u]; zg += p[2 * HH + u]; zo += p[3 * HH + u];
      }
      const float* wrow = Wi + (size_t)tok * ZC;
      zi += wrow[u]; zf += wrow[HH + u]; zg += wrow[2 * HH + u]; zo += wrow[3 * HH + u];
    }
    const float cprev = (t == 0) ? c0[b * HH + u] : cbuf[b * HH + u];
    const float cc = sigf(zf) * cprev + sigf(zi) * tanhf(zg);
    const float hh = sigf(zo) * tanhf(cc);
    cbuf[b * HH + u] = cc;
    hbuf[b * HH + u] = hh;
  }
}

// ---------------------------------------------------------------------------
// kA: part[s][b][col] partials for [h@Wp | h@Wh].
// grid = 96 colblk(128 cols) x 4 uslice(256 u) x 2 bgroup(16 b) = 768 blocks
// (3 blocks/CU, 12 waves/CU). Block: 4 waves = (uhalf: 128 u) x (bq: 8 b);
// within a wave lanes 0-31 / 32-63 cover the SAME 128 cols (4/lane, float4)
// but different 4-batch sets -> acc = 4 x float4 = 16 VGPR. h broadcast from
// 16 KB LDS (2 distinct addrs per wave read = free). Weight elements read
// once per bgroup (x2 total). LDS reused as reduce buffer (barrier-guarded).
__global__ __launch_bounds__(256) void kA(
    const float* __restrict__ hbuf,     // [B][H]
    const float* __restrict__ Wp,       // [H][V]
    const float* __restrict__ Wh,       // [H][ZC]
    float* __restrict__ part)           // [SPL][B][NCOL]
{
  constexpr int NCB = NCOL / 128;       // 96 col-blocks
  const int cb = blockIdx.x % NCB;
  const int s  = (blockIdx.x / NCB) % SPL;
  const int bg = blockIdx.x / (NCB * SPL);   // 0/1

  const int tid     = threadIdx.x;
  const int lane    = tid & 63;
  const int w       = tid >> 6;
  const int uhalf   = w >> 1;           // 0/1: which 128-u half
  const int bq      = w & 1;            // 0/1: which 8-batch quarter-pair
  const int lane_c  = lane & 31;        // 32 col-groups of 4
  const int lane_bh = lane >> 5;        // 0/1: which 4-batch set
  const int colbase = cb * 128;

  const float* W; int ldw, wcol;
  if (colbase < VV) { W = Wp; ldw = VV; wcol = colbase + lane_c * 4; }
  else              { W = Wh; ldw = ZC; wcol = colbase - VV + lane_c * 4; }

  // hs[b_local][u] floats, b_local in [0,16), u in [0,256): 16 KB.
  __shared__ __align__(16) float smem[16 * 256];

  const int u0 = s * 256;
  // stage: 1024 float4, 256 threads -> 4 each, coalesced.
#pragma unroll
  for (int k = 0; k < 4; ++k) {
    const int j = tid + k * 256;            // float4 index
    const int b = j >> 6;                   // 64 float4 per 256-float row
    const int uu = (j & 63) * 4;
    *(float4*)&smem[b * 256 + uu] =
        *(const float4*)&hbuf[(bg * 16 + b) * HH + u0 + uu];
  }
  __syncthreads();

  float4 acc[4];
#pragma unroll
  for (int i = 0; i < 4; ++i) acc[i] = make_float4(0.f, 0.f, 0.f, 0.f);

  const int bloc0 = bq * 8 + lane_bh * 4;   // this lane's 4 batches (local)
  const float* wp = W + (size_t)(u0 + uhalf * 128) * ldw + wcol;
  const float* hbase = &smem[bloc0 * 256 + uhalf * 128];

#pragma unroll 1
  for (int uc = 0; uc < 16; ++uc) {
    float4 wv[8];
#pragma unroll
    for (int k = 0; k < 8; ++k)
      wv[k] = *(const float4*)&wp[(size_t)k * ldw];
    wp += (size_t)8 * ldw;
#pragma unroll
    for (int bl = 0; bl < 4; ++bl) {
      const float* hrow = hbase + bl * 256 + uc * 8;
      const float4 ha = *(const float4*)&hrow[0];
      const float4 hb = *(const float4*)&hrow[4];
      float4 a = acc[bl];
      a.x = fmaf(wv[0].x, ha.x, a.x); a.y = fmaf(wv[0].y, ha.x, a.y);
      a.z = fmaf(wv[0].z, ha.x, a.z); a.w = fmaf(wv[0].w, ha.x, a.w);
      a.x = fmaf(wv[1].x, ha.y, a.x); a.y = fmaf(wv[1].y, ha.y, a.y);
      a.z = fmaf(wv[1].z, ha.y, a.z); a.w = fmaf(wv[1].w, ha.y, a.w);
      a.x = fmaf(wv[2].x, ha.z, a.x); a.y = fmaf(wv[2].y, ha.z, a.y);
      a.z = fmaf(wv[2].z, ha.z, a.z); a.w = fmaf(wv[2].w, ha.z, a.w);
      a.x = fmaf(wv[3].x, ha.w, a.x); a.y = fmaf(wv[3].y, ha.w, a.y);
      a.z = fmaf(wv[3].z, ha.w, a.z); a.w = fmaf(wv[3].w, ha.w, a.w);
      a.x = fmaf(wv[4].x, hb.x, a.x); a.y = fmaf(wv[4].y, hb.x, a.y);
      a.z = fmaf(wv[4].z, hb.x, a.z); a.w = fmaf(wv[4].w, hb.x, a.w);
      a.x = fmaf(wv[5].x, hb.y, a.x); a.y = fmaf(wv[5].y, hb.y, a.y);
      a.z = fmaf(wv[5].z, hb.y, a.z); a.w = fmaf(wv[5].w, hb.y, a.w);
      a.x = fmaf(wv[6].x, hb.z, a.x); a.y = fmaf(wv[6].y, hb.z, a.y);
      a.z = fmaf(wv[6].z, hb.z, a.z); a.w = fmaf(wv[6].w, hb.z, a.w);
      a.x = fmaf(wv[7].x, hb.w, a.x); a.y = fmaf(wv[7].y, hb.w, a.y);
      a.z = fmaf(wv[7].z, hb.w, a.z); a.w = fmaf(wv[7].w, hb.w, a.w);
      acc[bl] = a;
    }
  }

  // Epilogue: sum the two uhalf contributions per (b_local, col).
  // red[b_local(16)][uhalf(2)][col-group(32)] float4 = 16 KB, aliases smem.
  __syncthreads();   // all smem h-reads complete
  float4* red = (float4*)smem;
#pragma unroll
  for (int bl = 0; bl < 4; ++bl)
    red[((bloc0 + bl) * 2 + uhalf) * 32 + lane_c] = acc[bl];
  __syncthreads();
#pragma unroll
  for (int rep = 0; rep < 2; ++rep) {
    const int i = rep * 256 + tid;          // 0..511
    const int bl = i >> 5;                  // b_local 0..15
    const int cq = i & 31;                  // col-group 0..31
    const float4 r0 = red[(bl * 2 + 0) * 32 + cq];
    const float4 r1 = red[(bl * 2 + 1) * 32 + cq];
    float4 o;
    o.x = r0.x + r1.x; o.y = r0.y + r1.y;
    o.z = r0.z + r1.z; o.w = r0.w + r1.w;
    *(float4*)&part[((size_t)s * BB + bg * 16 + bl) * NCOL + colbase + cq * 4] = o;
  }
}

// ---------------------------------------------------------------------------
// K3: logits = sum_s part (static unroll) + bp -> out; preds zero; gumbel;
// per-block argmax partial.  grid: B*32 = 1024 blocks, 256 thr.  [R6-proven]
__global__ __launch_bounds__(256) void k3_logits(
    const float* __restrict__ part,     // [SPL][B][NCOL]
    const float* __restrict__ bp,       // [V]
    float* __restrict__ logits_out,     // [B][T][V]
    float* __restrict__ preds_out,      // [B][T][V]
    float* __restrict__ argval, int* __restrict__ argidx,   // [B][32]
    uint32_t ck0, uint32_t ck1, int t)
{
  const int b  = blockIdx.x >> 5;
  const int ch = blockIdx.x & 31;
  const int v  = ch * 256 + threadIdx.x;

  float lg = bp[v];
#pragma unroll
  for (int s = 0; s < SPL; ++s) lg += part[((size_t)s * BB + b) * NCOL + v];
  logits_out[((size_t)b * TT + t) * VV + v] = lg;
  preds_out [((size_t)b * TT + t) * VV + v] = 0.0f;

  // gumbel: jax partitionable random_bits, 32-bit -> o0 ^ o1
  const uint32_t j = (uint32_t)(b * VV + v);
  uint32_t r0, r1;
  tf2x32(ck0, ck1, 0u, j, r0, r1);
  const uint32_t bits = r0 ^ r1;
  const float u0 = __uint_as_float((bits >> 9) | 0x3f800000u) - 1.0f;
  const float uu = (u0 == 0.0f) ? 1.17549435e-38f : u0;
  const float g = -logf(-logf(uu));
  const float val = lg + g;

  __shared__ float sval[256];
  __shared__ int   sidx[256];
  sval[threadIdx.x] = val;
  sidx[threadIdx.x] = v;
  __syncthreads();
#pragma unroll
  for (int off = 128; off; off >>= 1) {
    if (threadIdx.x < off) {
      const float vo = sval[threadIdx.x + off];
      const int   io = sidx[threadIdx.x + off];
      if (vo > sval[threadIdx.x] ||
          (vo == sval[threadIdx.x] && io < sidx[threadIdx.x])) {
        sval[threadIdx.x] = vo; sidx[threadIdx.x] = io;
      }
    }
    __syncthreads();
  }
  if (threadIdx.x == 0) {
    argval[b * 32 + ch] = sval[0];
    argidx[b * 32 + ch] = sidx[0];
  }
}

// Final preds row (t = T-1).
__global__ __launch_bounds__(64) void kfinal(
    const float* __restrict__ argval, const int* __restrict__ argidx,
    float* __restrict__ preds_out)
{
  const int b = blockIdx.x, lane = threadIdx.x;
  float v = -3.4e38f; int idx = 0x7fffffff;
  if (lane < 32) { v = argval[b * 32 + lane]; idx = argidx[b * 32 + lane]; }
#pragma unroll
  for (int off = 16; off; off >>= 1) {
    const float vo = __shfl_down(v, off);
    const int   io = __shfl_down(idx, off);
    if (vo > v || (vo == v && io < idx)) { v = vo; idx = io; }
  }
  if (lane == 0) preds_out[((size_t)b * TT + (TT - 1)) * VV + idx] = 1.0f;
}

}  // namespace

extern "C" void kernel_launch(void* const* d_in, const int* in_sizes, int n_in,
                              void* d_out, int out_size, void* d_ws, size_t ws_size,
                              hipStream_t stream) {
  const float* inputs = (const float*)d_in[0];
  const float* Wi     = (const float*)d_in[1];
  const float* Wh     = (const float*)d_in[2];
  const float* bh     = (const float*)d_in[3];
  const float* Wp     = (const float*)d_in[4];
  const float* bp     = (const float*)d_in[5];
  const float* c0     = (const float*)d_in[6];
  const float* h0     = (const float*)d_in[7];

  float* out_logits = (float*)d_out;
  float* out_preds  = out_logits + (size_t)BB * TT * VV;

  uint8_t* ws = (uint8_t*)d_ws;
  const size_t partB = (size_t)SPL * BB * NCOL * sizeof(float);   // 6.29 MB
  float* part   = (float*)ws;                 // [SPL][B][NCOL]
  float* zpart0 = (float*)ws;                 // [K0S][B][ZC] = 4 MB (overlap)
  size_t off = partB;
  float* zfull0 = (float*)(ws + off); off += (size_t)BB * ZC * sizeof(float);
  float* cbuf   = (float*)(ws + off); off += (size_t)BB * HH * sizeof(float);
  float* hbuf   = (float*)(ws + off); off += (size_t)BB * HH * sizeof(float);
  float* argval = (float*)(ws + off); off += (size_t)BB * 32 * sizeof(float);
  int*   argidx = (int*)  (ws + off); off += (size_t)BB * 32 * sizeof(int);

  // Host-side threefry key chain from jax.random.key(42) = (0, 42).
  uint32_t k0 = 0u, k1 = 42u;
  uint32_t ck[TT][2];
  for (int t = 0; t < TT; ++t) {
    uint32_t a, b2; tf2x32(k0, k1, 0u, 1u, a, b2);
    ck[t][0] = a; ck[t][1] = b2;
    uint32_t n0, n1; tf2x32(k0, k1, 0u, 0u, n0, n1);
    k0 = n0; k1 = n1;
  }

  k0_partial<<<(ZC / 64) * K0S, 256, 0, stream>>>(inputs, h0, Wi, Wh, zpart0);
  k0_reduce<<<BB * ZC / 256, 256, 0, stream>>>(zpart0, bh, zfull0);

  for (int t = 0; t < TT; ++t) {
    k1_cell<<<BB, 256, 0, stream>>>(part, zfull0, bh, Wi, c0, argval,
                                    argidx, cbuf, hbuf, out_preds, t);
    kA<<<(NCOL / 128) * SPL * 2, 256, 0, stream>>>(hbuf, Wp, Wh, part);
    k3_logits<<<BB * 32, 256, 0, stream>>>(part, bp, out_logits, out_preds,
                                           argval, argidx, ck[t][0], ck[t][1], t);
  }
  kfinal<<<BB, 64, 0, stream>>>(argval, argidx, out_preds);
}